// Round 1
// baseline (1169.487 us; speedup 1.0000x reference)
//
#include <hip/hip_runtime.h>
#include <cfloat>

#define BATCH 4
#define P 8192
#define C 64
#define KNN 16
#define NPTS (BATCH * P)        // 32768
#define NEDGE (NPTS * KNN)      // 524288
#define EPSV 1e-5f
#define SLOPE 0.2f

// ---------------- workspace layout (float element offsets) ----------------
// U      : [NPTS][C]   @ 0          (2097152)
// V      : [NPTS][C]   @ 2097152    (2097152)
// sq     : [NPTS]      @ 4194304    (32768)
// stats  : [128]       @ 4227072    (sum[64], sumsq[64])
// sshift : [128]       @ 4227200    (scale[64], shift[64])
// idx    : int[NEDGE]  @ 4227328 (as int*)
// total ~19.0 MB

// ---------------------------------------------------------------------------
// K1: U = x @ (W1 - W2), V = x @ W2, sq = rowwise |x|^2
// ---------------------------------------------------------------------------
__global__ void prep_kernel(const float* __restrict__ x, const float* __restrict__ W,
                            float* __restrict__ U, float* __restrict__ V,
                            float* __restrict__ sq) {
    __shared__ float Ws[128][64];   // 32 KB
    __shared__ float xs[4][64];
    int tid = threadIdx.x;
    for (int i = tid; i < 128 * 64; i += 256) ((float*)Ws)[i] = W[i];
    int p0 = blockIdx.x * 4;
    int r = tid >> 6, c = tid & 63;
    xs[r][c] = x[(size_t)(p0 + r) * C + c];
    __syncthreads();
    float u = 0.f, v = 0.f;
#pragma unroll
    for (int k = 0; k < 64; ++k) {
        float xv = xs[r][k];            // broadcast
        float w1 = Ws[k][c];
        float w2 = Ws[64 + k][c];
        u = fmaf(xv, w1 - w2, u);
        v = fmaf(xv, w2, v);
    }
    size_t o = (size_t)(p0 + r) * C + c;
    U[o] = u;
    V[o] = v;
    if (c == 0) {
        float s = 0.f;
#pragma unroll
        for (int k = 0; k < 64; ++k) s = fmaf(xs[r][k], xs[r][k], s);
        sq[p0 + r] = s;
    }
}

// ---------------------------------------------------------------------------
// top-k (k=16 smallest) register maintenance; arrays stay in VGPRs (static
// indexing after unroll, cndmask for the dynamic position).
// ---------------------------------------------------------------------------
__device__ __forceinline__ void tk_insert(float (&v)[16], int (&id)[16],
                                          float& worst, float s, int cand) {
    if (s < worst) {
        float w = v[0];
        int pos = 0;
#pragma unroll
        for (int j = 1; j < 16; ++j) {
            bool g = v[j] > w;
            w = g ? v[j] : w;
            pos = g ? j : pos;
        }
#pragma unroll
        for (int j = 0; j < 16; ++j) {
            if (j == pos) { v[j] = s; id[j] = cand; }
        }
        float nw = v[0];
#pragma unroll
        for (int j = 1; j < 16; ++j) nw = fmaxf(nw, v[j]);
        worst = nw;
    }
}

// ---------------------------------------------------------------------------
// K2: KNN. One WG per (batch, 64-row tile). 128 col-chunks of 64.
// score(p,q) = sq[q] - 2*dot(x_p, x_q)   (row term dropped: ranking-invariant)
// ---------------------------------------------------------------------------
__global__ __launch_bounds__(256, 2) void knn_kernel(const float* __restrict__ x,
                                                     const float* __restrict__ sq,
                                                     int* __restrict__ idx_out) {
    __shared__ float rowsT[64][68];   // [k][r], stride 68 keeps 16B align + 2-way banks
    __shared__ float colsT[64][68];   // [k][c]; reused as merge idx buffer
    __shared__ float scores[64][65];  // [r][c]
    __shared__ float sqc[64];

    int tid = threadIdx.x;
    int b = blockIdx.x & 3;          // XCD-affine: batch b lands on XCDs {b, b+4}
    int tile = blockIdx.x >> 2;
    int bglob = b * P;
    int r0 = tile * 64;
    const float* xb = x + (size_t)bglob * C;

    // stage row tile transposed
    {
        int r = tid & 63;
        int j0 = (tid >> 6) * 16;
        const float4* s4 = reinterpret_cast<const float4*>(xb + (size_t)(r0 + r) * C + j0);
        float4 a0 = s4[0], a1 = s4[1], a2 = s4[2], a3 = s4[3];
        float tmp[16] = {a0.x, a0.y, a0.z, a0.w, a1.x, a1.y, a1.z, a1.w,
                         a2.x, a2.y, a2.z, a2.w, a3.x, a3.y, a3.z, a3.w};
#pragma unroll
        for (int j = 0; j < 16; ++j) rowsT[j0 + j][r] = tmp[j];
    }

    int tr = tid & 15, tc = tid >> 4;
    int selr = tid & 63, selsub = tid >> 6;

    float tv[16];
    int ti[16];
    float worst = FLT_MAX;
#pragma unroll
    for (int j = 0; j < 16; ++j) { tv[j] = FLT_MAX; ti[j] = 0; }

    for (int chunk = 0; chunk < P / 64; ++chunk) {
        int c0 = chunk * 64;
        __syncthreads();  // A: prior selection done before colsT overwrite
        {
            int cc = tid & 63;
            int j0 = (tid >> 6) * 16;
            const float4* s4 = reinterpret_cast<const float4*>(xb + (size_t)(c0 + cc) * C + j0);
            float4 a0 = s4[0], a1 = s4[1], a2 = s4[2], a3 = s4[3];
            float tmp[16] = {a0.x, a0.y, a0.z, a0.w, a1.x, a1.y, a1.z, a1.w,
                             a2.x, a2.y, a2.z, a2.w, a3.x, a3.y, a3.z, a3.w};
#pragma unroll
            for (int j = 0; j < 16; ++j) colsT[j0 + j][cc] = tmp[j];
            if (tid < 64) sqc[tid] = sq[bglob + c0 + tid];
        }
        __syncthreads();  // B: staging visible

        float acc[4][4] = {{0.f, 0.f, 0.f, 0.f}, {0.f, 0.f, 0.f, 0.f},
                           {0.f, 0.f, 0.f, 0.f}, {0.f, 0.f, 0.f, 0.f}};
#pragma unroll 8
        for (int k = 0; k < C; ++k) {
            float4 av = *reinterpret_cast<const float4*>(&rowsT[k][4 * tr]);
            float4 bv = *reinterpret_cast<const float4*>(&colsT[k][4 * tc]);
            float a4[4] = {av.x, av.y, av.z, av.w};
            float b4[4] = {bv.x, bv.y, bv.z, bv.w};
#pragma unroll
            for (int i = 0; i < 4; ++i)
#pragma unroll
                for (int j = 0; j < 4; ++j) acc[i][j] = fmaf(a4[i], b4[j], acc[i][j]);
        }
#pragma unroll
        for (int i = 0; i < 4; ++i)
#pragma unroll
            for (int j = 0; j < 4; ++j)
                scores[4 * tr + i][4 * tc + j] = sqc[4 * tc + j] - 2.f * acc[i][j];
        __syncthreads();  // C: scores visible

#pragma unroll
        for (int j = 0; j < 16; ++j) {
            int ccol = selsub * 16 + j;
            tk_insert(tv, ti, worst, scores[selr][ccol], bglob + c0 + ccol);
        }
    }

    // merge the 4 partial lists per row
    __syncthreads();
    int* idLDS = (int*)&colsT[0][0];  // [r*65 + e]
#pragma unroll
    for (int j = 0; j < 16; ++j) {
        scores[selr][selsub * 16 + j] = tv[j];
        idLDS[selr * 65 + selsub * 16 + j] = ti[j];
    }
    __syncthreads();
    if (tid < 64) {
        float mv[16];
        int mid[16];
        float mworst = FLT_MAX;
#pragma unroll
        for (int j = 0; j < 16; ++j) { mv[j] = FLT_MAX; mid[j] = 0; }
        for (int e = 0; e < 64; ++e)
            tk_insert(mv, mid, mworst, scores[tid][e], idLDS[tid * 65 + e]);
        size_t o = ((size_t)bglob + r0 + tid) * KNN;
#pragma unroll
        for (int j = 0; j < 16; ++j) idx_out[o + j] = mid[j];
    }
}

// ---------------------------------------------------------------------------
// K3: BN stats.  h[p,k][c] = U[p][c] + b[c] + V[idx[p,k]][c]
// one block per 32 points; per-thread partials, LDS reduce, 1 atomic/channel
// ---------------------------------------------------------------------------
__global__ void stats_kernel(const float* __restrict__ U, const float* __restrict__ V,
                             const float* __restrict__ bias, const int* __restrict__ idx,
                             float* __restrict__ stats) {
    int tid = threadIdx.x;
    int c = tid & 63, kk = tid >> 6;  // kk in 0..3, k = kk*4 + k4
    int p0 = blockIdx.x * 32;
    float bc = bias[c];
    float sum = 0.f, sumsq = 0.f;
    for (int pp = 0; pp < 32; ++pp) {
        int p = p0 + pp;
        float u = U[(size_t)p * C + c] + bc;
#pragma unroll
        for (int k4 = 0; k4 < 4; ++k4) {
            int j = idx[(size_t)p * KNN + kk * 4 + k4];
            float h = u + V[(size_t)j * C + c];
            sum += h;
            sumsq = fmaf(h, h, sumsq);
        }
    }
    __shared__ float red[2][4][64];
    red[0][kk][c] = sum;
    red[1][kk][c] = sumsq;
    __syncthreads();
    if (tid < 64) {
        float s = red[0][0][tid] + red[0][1][tid] + red[0][2][tid] + red[0][3][tid];
        atomicAdd(&stats[tid], s);
    } else if (tid < 128) {
        int cc = tid - 64;
        float s = red[1][0][cc] + red[1][1][cc] + red[1][2][cc] + red[1][3][cc];
        atomicAdd(&stats[64 + cc], s);
    }
}

// ---------------------------------------------------------------------------
// K4: finalize BN scale/shift
// ---------------------------------------------------------------------------
__global__ void finalize_kernel(const float* __restrict__ stats,
                                const float* __restrict__ gamma,
                                const float* __restrict__ beta,
                                float* __restrict__ sshift) {
    int c = threadIdx.x;
    const float N = (float)NEDGE;
    float mean = stats[c] / N;
    float var = stats[64 + c] / N - mean * mean;
    float s = gamma[c] * rsqrtf(var + EPSV);
    sshift[c] = s;
    sshift[64 + c] = beta[c] - mean * s;
}

// ---------------------------------------------------------------------------
// K5: out[p][c] = lrelu(s*(U+b + max/min_k V[idx]) + t)
// (max_k and lrelu/affine commute since both monotone; use min when s<0)
// ---------------------------------------------------------------------------
__global__ void out_kernel(const float* __restrict__ U, const float* __restrict__ V,
                           const float* __restrict__ bias, const int* __restrict__ idx,
                           const float* __restrict__ sshift, float* __restrict__ out) {
    int tid = threadIdx.x;
    int c = tid & 63, g = tid >> 6;
    int p0 = blockIdx.x * 16;
    float s = sshift[c], t = sshift[64 + c];
    float bc = bias[c];
    for (int pp = g; pp < 16; pp += 4) {
        int p = p0 + pp;
        float mx = -FLT_MAX, mn = FLT_MAX;
#pragma unroll
        for (int k = 0; k < KNN; ++k) {
            int j = idx[(size_t)p * KNN + k];
            float v = V[(size_t)j * C + c];
            mx = fmaxf(mx, v);
            mn = fminf(mn, v);
        }
        float hsel = (s >= 0.f) ? mx : mn;
        float hn = fmaf(s, U[(size_t)p * C + c] + bc + hsel, t);
        out[(size_t)p * C + c] = (hn >= 0.f) ? hn : SLOPE * hn;
    }
}

// ---------------------------------------------------------------------------
extern "C" void kernel_launch(void* const* d_in, const int* in_sizes, int n_in,
                              void* d_out, int out_size, void* d_ws, size_t ws_size,
                              hipStream_t stream) {
    const float* x     = (const float*)d_in[0];
    // d_in[1] = batch (int64) — structure is known (B contiguous blocks of P), unused
    const float* W     = (const float*)d_in[2];
    const float* bias  = (const float*)d_in[3];
    const float* gamma = (const float*)d_in[4];
    const float* beta  = (const float*)d_in[5];
    float* out = (float*)d_out;

    float* wsf    = (float*)d_ws;
    float* U      = wsf;
    float* V      = wsf + 2097152;
    float* sq     = wsf + 4194304;
    float* stats  = wsf + 4227072;
    float* sshift = wsf + 4227200;
    int*   idx    = (int*)(wsf + 4227328);

    hipLaunchKernelGGL(prep_kernel, dim3(NPTS / 4), dim3(256), 0, stream, x, W, U, V, sq);
    hipLaunchKernelGGL(knn_kernel, dim3(BATCH * (P / 64)), dim3(256), 0, stream, x, sq, idx);
    hipMemsetAsync(stats, 0, 128 * sizeof(float), stream);
    hipLaunchKernelGGL(stats_kernel, dim3(NPTS / 32), dim3(256), 0, stream, U, V, bias, idx, stats);
    hipLaunchKernelGGL(finalize_kernel, dim3(1), dim3(64), 0, stream, stats, gamma, beta, sshift);
    hipLaunchKernelGGL(out_kernel, dim3(NPTS / 16), dim3(256), 0, stream, U, V, bias, idx, sshift, out);
}

// Round 2
// 590.058 us; speedup vs baseline: 1.9820x; 1.9820x over previous
//
#include <hip/hip_runtime.h>
#include <cfloat>

#define BATCH 4
#define P 8192
#define C 64
#define KNN 16
#define NPTS (BATCH * P)        // 32768
#define NEDGE (NPTS * KNN)      // 524288
#define EPSV 1e-5f
#define SLOPE 0.2f
#define CAP 16

typedef __attribute__((ext_vector_type(8))) short bf16x8;
typedef __attribute__((ext_vector_type(16))) float f32x16;

// ---------------- workspace layout (float element offsets) ----------------
// U      : [NPTS][C]   @ 0          (2097152)   written AFTER knn
// V      : [NPTS][C]   @ 2097152    (2097152)   written AFTER knn
// xfh    : bf16 frag   @ 0          (1048576 float-slots)  \  alias U/V region,
// xfm    : bf16 frag   @ 1048576    (1048576)               } dead after knn
// xfl    : bf16 frag   @ 2097152    (1048576)              /
// sq     : [NPTS]      @ 4194304    (32768)
// stats  : [128]       @ 4227072
// sshift : [128]       @ 4227200
// idx    : int[NEDGE]  @ 4227328
// total = 4751616 floats = 18.1 MB (same footprint as round 1)

// ---------------------------------------------------------------------------
// bf16 helpers (manual RNE, no NaN expected in this data)
// ---------------------------------------------------------------------------
__device__ __forceinline__ unsigned short f2bf(float f) {
    unsigned u = __float_as_uint(f);
    u += 0x7FFFu + ((u >> 16) & 1u);
    return (unsigned short)(u >> 16);
}
__device__ __forceinline__ float bf2f(unsigned short s) {
    return __uint_as_float(((unsigned)s) << 16);
}

// ---------------------------------------------------------------------------
// K0: fragment-layout 3-way bf16 split of x, plus exact fp32 row norms.
// Fragment global layout: xf[(g*4+kk)*64 + lane] (uint4 = 8 bf16) holds
// point g*32+(lane&31), k = kk*16 + (lane>>5)*8 .. +8  — exactly the MFMA
// A/B operand mapping for v_mfma_f32_32x32x16_bf16.
// ---------------------------------------------------------------------------
__global__ void prep_frag(const float* __restrict__ x, uint4* __restrict__ xfh,
                          uint4* __restrict__ xfm, uint4* __restrict__ xfl,
                          float* __restrict__ sq) {
    __shared__ float part[32][9];
    int tid = threadIdx.x;
    int ptl = tid >> 3, j8 = tid & 7;
    int g = blockIdx.x;
    int p = g * 32 + ptl;
    const float4* xp = (const float4*)(x + (size_t)p * C + j8 * 8);
    float4 a = xp[0], b = xp[1];
    float v[8] = {a.x, a.y, a.z, a.w, b.x, b.y, b.z, b.w};
    unsigned short hs[8], ms[8], ls[8];
    float ssum = 0.f;
#pragma unroll
    for (int e = 0; e < 8; ++e) {
        float xv = v[e];
        ssum = fmaf(xv, xv, ssum);
        unsigned short h = f2bf(xv);
        float r1 = xv - bf2f(h);
        unsigned short m = f2bf(r1);
        float r2 = r1 - bf2f(m);
        unsigned short l = f2bf(r2);
        hs[e] = h; ms[e] = m; ls[e] = l;
    }
    int dst = (g * 4 + (j8 >> 1)) * 64 + ptl + 32 * (j8 & 1);
    uint4 ph, pm, pl;
    ph.x = (unsigned)hs[0] | ((unsigned)hs[1] << 16);
    ph.y = (unsigned)hs[2] | ((unsigned)hs[3] << 16);
    ph.z = (unsigned)hs[4] | ((unsigned)hs[5] << 16);
    ph.w = (unsigned)hs[6] | ((unsigned)hs[7] << 16);
    pm.x = (unsigned)ms[0] | ((unsigned)ms[1] << 16);
    pm.y = (unsigned)ms[2] | ((unsigned)ms[3] << 16);
    pm.z = (unsigned)ms[4] | ((unsigned)ms[5] << 16);
    pm.w = (unsigned)ms[6] | ((unsigned)ms[7] << 16);
    pl.x = (unsigned)ls[0] | ((unsigned)ls[1] << 16);
    pl.y = (unsigned)ls[2] | ((unsigned)ls[3] << 16);
    pl.z = (unsigned)ls[4] | ((unsigned)ls[5] << 16);
    pl.w = (unsigned)ls[6] | ((unsigned)ls[7] << 16);
    xfh[dst] = ph; xfm[dst] = pm; xfl[dst] = pl;
    part[ptl][j8] = ssum;
    __syncthreads();
    if (j8 == 0) {
        float s = 0.f;
#pragma unroll
        for (int k = 0; k < 8; ++k) s += part[ptl][k];
        sq[p] = s;
    }
}

// ---------------------------------------------------------------------------
// top-16-smallest register list maintenance (replace-max)
// ---------------------------------------------------------------------------
__device__ __forceinline__ void tk_insert(float (&v)[16], int (&id)[16],
                                          float& worst, float s, int cand) {
    if (s < worst) {
        float w = v[0];
        int pos = 0;
#pragma unroll
        for (int j = 1; j < 16; ++j) {
            bool g = v[j] > w;
            w = g ? v[j] : w;
            pos = g ? j : pos;
        }
#pragma unroll
        for (int j = 0; j < 16; ++j) {
            if (j == pos) { v[j] = s; id[j] = cand; }
        }
        float nw = v[0];
#pragma unroll
        for (int j = 1; j < 16; ++j) nw = fmaxf(nw, v[j]);
        worst = nw;
    }
}

// ---------------------------------------------------------------------------
// K1: KNN via MFMA Gram + deferred selection.
// WG = (batch, 64-row tile); 4 waves each own a 32x32 quadrant per 64-col chunk.
// ---------------------------------------------------------------------------
__global__ __launch_bounds__(256, 2) void knn_kernel(const uint4* __restrict__ xfh,
                                                     const uint4* __restrict__ xfm,
                                                     const uint4* __restrict__ xfl,
                                                     const float* __restrict__ sq,
                                                     int* __restrict__ idx_out) {
    __shared__ float scoresL[64 * 65];   // [row][col], stride 65 -> 2-way banks
    __shared__ float bufv[64 * 17];      // stride 17 -> conflict-free owner reads
    __shared__ int   bufi[64 * 17];
    __shared__ int   cntL[64];
    __shared__ float worstL[64];

    int tid = threadIdx.x;
    int b = blockIdx.x & 3;              // batch b -> XCDs {b, b+4}: frags L2-resident
    int tile = blockIdx.x >> 2;
    int bglob = b * P;
    int r0 = tile * 64;
    int w = tid >> 6, lane = tid & 63;
    int wr = w & 1, wc = w >> 1;

    if (tid < 64) { cntL[tid] = 0; worstL[tid] = FLT_MAX; }

    // persistent A fragments for this wave's 32 rows (48 VGPRs)
    int gA = ((bglob + r0) >> 5) + wr;
    bf16x8 Ah[4], Am[4], Al[4];
#pragma unroll
    for (int kk = 0; kk < 4; ++kk) {
        Ah[kk] = __builtin_bit_cast(bf16x8, xfh[(gA * 4 + kk) * 64 + lane]);
        Am[kk] = __builtin_bit_cast(bf16x8, xfm[(gA * 4 + kk) * 64 + lane]);
        Al[kk] = __builtin_bit_cast(bf16x8, xfl[(gA * 4 + kk) * 64 + lane]);
    }

    // owner state: thread (lane<16, wave w) owns row lane*4 + w
    float tv[16];
    int ti[16];
    float worst = FLT_MAX;
#pragma unroll
    for (int j = 0; j < 16; ++j) { tv[j] = FLT_MAX; ti[j] = 0; }
    int rown = ((lane & 15) << 2) | w;
    bool owner = (lane < 16);

    int selr = tid & 63;
    int selq = tid >> 6;

    for (int chunk = 0; chunk < P / 64; ++chunk) {
        int c0 = chunk * 64;
        int gB = ((bglob + c0) >> 5) + wc;
        bf16x8 Bh[4], Bm[4], Bl[4];
#pragma unroll
        for (int kk = 0; kk < 4; ++kk) {
            Bh[kk] = __builtin_bit_cast(bf16x8, xfh[(gB * 4 + kk) * 64 + lane]);
            Bm[kk] = __builtin_bit_cast(bf16x8, xfm[(gB * 4 + kk) * 64 + lane]);
            Bl[kk] = __builtin_bit_cast(bf16x8, xfl[(gB * 4 + kk) * 64 + lane]);
        }
        float sc = sq[bglob + c0 + wc * 32 + (lane & 31)];

        f32x16 acc0, acc1;   // two chains to break the dependent-MFMA latency
#pragma unroll
        for (int i = 0; i < 16; ++i) { acc0[i] = 0.f; acc1[i] = 0.f; }
#pragma unroll
        for (int kk = 0; kk < 4; ++kk) {
            acc0 = __builtin_amdgcn_mfma_f32_32x32x16_bf16(Ah[kk], Bh[kk], acc0, 0, 0, 0);
            acc1 = __builtin_amdgcn_mfma_f32_32x32x16_bf16(Ah[kk], Bm[kk], acc1, 0, 0, 0);
            acc0 = __builtin_amdgcn_mfma_f32_32x32x16_bf16(Am[kk], Bh[kk], acc0, 0, 0, 0);
            acc1 = __builtin_amdgcn_mfma_f32_32x32x16_bf16(Am[kk], Bm[kk], acc1, 0, 0, 0);
            acc0 = __builtin_amdgcn_mfma_f32_32x32x16_bf16(Ah[kk], Bl[kk], acc0, 0, 0, 0);
            acc1 = __builtin_amdgcn_mfma_f32_32x32x16_bf16(Al[kk], Bh[kk], acc1, 0, 0, 0);
        }

        __syncthreads();  // (1) prev merge done -> scoresL reusable
        {
            int colL = wc * 32 + (lane & 31);
            int rbase = wr * 32 + 4 * (lane >> 5);
#pragma unroll
            for (int reg = 0; reg < 16; ++reg) {
                int row = rbase + (reg & 3) + 8 * (reg >> 2);  // verified C/D mapping
                scoresL[row * 65 + colL] = fmaf(-2.f, acc0[reg] + acc1[reg], sc);
            }
        }
        __syncthreads();  // (2) scores visible
        {
            float wst = worstL[selr];
#pragma unroll
            for (int j = 0; j < 16; ++j) {
                float s = scoresL[selr * 65 + selq * 16 + j];
                if (s < wst) {
                    int slot = atomicAdd(&cntL[selr], 1);
                    if (slot < CAP) {
                        bufv[selr * 17 + slot] = s;
                        bufi[selr * 17 + slot] = c0 + selq * 16 + j;
                    }
                }
            }
        }
        __syncthreads();  // (3) appends visible
        if (owner) {
            int n = cntL[rown];
            if (n > 0) {
                if (n > CAP) {   // overflow (always chunk 0): rescan full row
                    for (int e = 0; e < 64; ++e)
                        tk_insert(tv, ti, worst, scoresL[rown * 65 + e], c0 + e);
                } else {
                    for (int k = 0; k < n; ++k)
                        tk_insert(tv, ti, worst, bufv[rown * 17 + k], bufi[rown * 17 + k]);
                }
                cntL[rown] = 0;
                worstL[rown] = worst;
            }
        }
    }

    if (owner) {
        size_t o = ((size_t)(bglob + r0 + rown)) * KNN;
#pragma unroll
        for (int j = 0; j < 16; ++j) idx_out[o + j] = bglob + ti[j];
    }
}

// ---------------------------------------------------------------------------
// K2: U = x @ (W1 - W2), V = x @ W2   (runs after knn; overwrites frag region)
// ---------------------------------------------------------------------------
__global__ void prep_UV(const float* __restrict__ x, const float* __restrict__ W,
                        float* __restrict__ U, float* __restrict__ V) {
    __shared__ float Ws[128][64];
    __shared__ float xs[4][64];
    int tid = threadIdx.x;
    for (int i = tid; i < 128 * 64; i += 256) ((float*)Ws)[i] = W[i];
    int p0 = blockIdx.x * 4;
    int r = tid >> 6, c = tid & 63;
    xs[r][c] = x[(size_t)(p0 + r) * C + c];
    __syncthreads();
    float u = 0.f, v = 0.f;
#pragma unroll
    for (int k = 0; k < 64; ++k) {
        float xv = xs[r][k];
        float w1 = Ws[k][c];
        float w2 = Ws[64 + k][c];
        u = fmaf(xv, w1 - w2, u);
        v = fmaf(xv, w2, v);
    }
    size_t o = (size_t)(p0 + r) * C + c;
    U[o] = u;
    V[o] = v;
}

// ---------------------------------------------------------------------------
// K3: BN stats
// ---------------------------------------------------------------------------
__global__ void stats_kernel(const float* __restrict__ U, const float* __restrict__ V,
                             const float* __restrict__ bias, const int* __restrict__ idx,
                             float* __restrict__ stats) {
    int tid = threadIdx.x;
    int c = tid & 63, kk = tid >> 6;
    int p0 = blockIdx.x * 32;
    float bc = bias[c];
    float sum = 0.f, sumsq = 0.f;
    for (int pp = 0; pp < 32; ++pp) {
        int p = p0 + pp;
        float u = U[(size_t)p * C + c] + bc;
#pragma unroll
        for (int k4 = 0; k4 < 4; ++k4) {
            int j = idx[(size_t)p * KNN + kk * 4 + k4];
            float h = u + V[(size_t)j * C + c];
            sum += h;
            sumsq = fmaf(h, h, sumsq);
        }
    }
    __shared__ float red[2][4][64];
    red[0][kk][c] = sum;
    red[1][kk][c] = sumsq;
    __syncthreads();
    if (tid < 64) {
        float s = red[0][0][tid] + red[0][1][tid] + red[0][2][tid] + red[0][3][tid];
        atomicAdd(&stats[tid], s);
    } else if (tid < 128) {
        int cc = tid - 64;
        float s = red[1][0][cc] + red[1][1][cc] + red[1][2][cc] + red[1][3][cc];
        atomicAdd(&stats[64 + cc], s);
    }
}

__global__ void finalize_kernel(const float* __restrict__ stats,
                                const float* __restrict__ gamma,
                                const float* __restrict__ beta,
                                float* __restrict__ sshift) {
    int c = threadIdx.x;
    const float N = (float)NEDGE;
    float mean = stats[c] / N;
    float var = stats[64 + c] / N - mean * mean;
    float s = gamma[c] * rsqrtf(var + EPSV);
    sshift[c] = s;
    sshift[64 + c] = beta[c] - mean * s;
}

// ---------------------------------------------------------------------------
// K5: out = lrelu(s*(U+b + max/min_k V[idx]) + t)  (monotone fusion of max_k)
// ---------------------------------------------------------------------------
__global__ void out_kernel(const float* __restrict__ U, const float* __restrict__ V,
                           const float* __restrict__ bias, const int* __restrict__ idx,
                           const float* __restrict__ sshift, float* __restrict__ out) {
    int tid = threadIdx.x;
    int c = tid & 63, g = tid >> 6;
    int p0 = blockIdx.x * 16;
    float s = sshift[c], t = sshift[64 + c];
    float bc = bias[c];
    for (int pp = g; pp < 16; pp += 4) {
        int p = p0 + pp;
        float mx = -FLT_MAX, mn = FLT_MAX;
#pragma unroll
        for (int k = 0; k < KNN; ++k) {
            int j = idx[(size_t)p * KNN + k];
            float v = V[(size_t)j * C + c];
            mx = fmaxf(mx, v);
            mn = fminf(mn, v);
        }
        float hsel = (s >= 0.f) ? mx : mn;
        float hn = fmaf(s, U[(size_t)p * C + c] + bc + hsel, t);
        out[(size_t)p * C + c] = (hn >= 0.f) ? hn : SLOPE * hn;
    }
}

// ---------------------------------------------------------------------------
extern "C" void kernel_launch(void* const* d_in, const int* in_sizes, int n_in,
                              void* d_out, int out_size, void* d_ws, size_t ws_size,
                              hipStream_t stream) {
    const float* x     = (const float*)d_in[0];
    const float* W     = (const float*)d_in[2];
    const float* bias  = (const float*)d_in[3];
    const float* gamma = (const float*)d_in[4];
    const float* beta  = (const float*)d_in[5];
    float* out = (float*)d_out;

    float* wsf    = (float*)d_ws;
    float* U      = wsf;
    float* V      = wsf + 2097152;
    uint4* xfh    = (uint4*)wsf;                   // aliases U/V, dead after knn
    uint4* xfm    = (uint4*)(wsf + 1048576);
    uint4* xfl    = (uint4*)(wsf + 2097152);
    float* sq     = wsf + 4194304;
    float* stats  = wsf + 4227072;
    float* sshift = wsf + 4227200;
    int*   idx    = (int*)(wsf + 4227328);

    hipLaunchKernelGGL(prep_frag, dim3(NPTS / 32), dim3(256), 0, stream, x, xfh, xfm, xfl, sq);
    hipLaunchKernelGGL(knn_kernel, dim3(BATCH * (P / 64)), dim3(256), 0, stream,
                       (const uint4*)xfh, (const uint4*)xfm, (const uint4*)xfl, sq, idx);
    hipLaunchKernelGGL(prep_UV, dim3(NPTS / 4), dim3(256), 0, stream, x, W, U, V);
    hipMemsetAsync(stats, 0, 128 * sizeof(float), stream);
    hipLaunchKernelGGL(stats_kernel, dim3(NPTS / 32), dim3(256), 0, stream, U, V, bias, idx, stats);
    hipLaunchKernelGGL(finalize_kernel, dim3(1), dim3(64), 0, stream, stats, gamma, beta, sshift);
    hipLaunchKernelGGL(out_kernel, dim3(NPTS / 16), dim3(256), 0, stream, U, V, bias, idx, sshift, out);
}